// Round 4
// baseline (935.703 us; speedup 1.0000x reference)
//
#include <hip/hip_runtime.h>
#include <math.h>

#define EPSF 1e-6f
#define NB   4
#define NC   3
#define HH   768
#define KS   31
#define KK   961
#define NHW  11
#define NN   121
#define NZ   14
#define HID  64

// workspace layout (float offsets)
#define XLIN_OFF  0
#define XLIN_SZ   (NB*NC*HH*HH)            // 7,077,888
#define BASIS_OFF (XLIN_OFF + XLIN_SZ)
#define MASK_OFF  (BASIS_OFF + 13456)      // basis needs 14*961=13454
#define COEF_OFF  (MASK_OFF + 964)         // mask needs 961
#define KERN_OFF  (COEF_OFF + 1696)        // coeffs need 121*14=1694
// kern needs 363*961 = 348,843 -> total ~29.8 MB

typedef float v2f __attribute__((ext_vector_type(2)));

__device__ __forceinline__ float hann_f(int p) {
    return 0.5f * (1.0f - cosf(6.283185307179586f * (float)p / 128.0f));
}

__global__ void k_pow(const float* __restrict__ x, const float* __restrict__ gp,
                      float* __restrict__ y, int n) {
    float g = *gp;
    for (int i = blockIdx.x * blockDim.x + threadIdx.x; i < n; i += gridDim.x * blockDim.x)
        y[i] = powf(fmaxf(x[i], 0.0f) + EPSF, g);
}

// Zernike-like polynomial basis, bit-exact mask vs numpy linspace semantics.
__global__ void k_basis(float* __restrict__ ws) {
    __shared__ float red[256];
    __shared__ float srms[NZ];
    __shared__ float scnt;
    float* basis = ws + BASIS_OFF;
    float* mask  = ws + MASK_OFF;
    int tid = threadIdx.x;
    double lsq[NZ];
    #pragma unroll
    for (int z = 0; z < NZ; ++z) lsq[z] = 0.0;
    double lcnt = 0.0;
    for (int pix = tid; pix < KK; pix += 256) {
        int i = pix / 31, j = pix - i * 31;
        double x = (j == 30) ? 1.0 : (-1.0 + (double)j * (2.0 / 30.0));
        double y = (i == 30) ? 1.0 : (-1.0 + (double)i * (2.0 / 30.0));
        double r2 = x * x + y * y;
        float m = (r2 <= 1.0) ? 1.0f : 0.0f;
        mask[pix] = m;
        lcnt += (double)m;
        #pragma unroll
        for (int deg = 1; deg <= 4; ++deg) {
            #pragma unroll
            for (int ii = 0; ii <= deg; ++ii) {
                const int z = deg * (deg + 1) / 2 - 1 + ii;
                double px = 1.0, py = 1.0;
                #pragma unroll
                for (int t = 0; t < deg - ii; ++t) px *= x;
                #pragma unroll
                for (int t = 0; t < ii; ++t) py *= y;
                float bf = (float)(px * py) * m;
                basis[z * KK + pix] = bf;
                lsq[z] += (double)bf * (double)bf;
            }
        }
    }
    for (int q = 0; q < NZ + 1; ++q) {
        red[tid] = (q < NZ) ? (float)lsq[q] : (float)lcnt;
        __syncthreads();
        for (int s = 128; s > 0; s >>= 1) {
            if (tid < s) red[tid] += red[tid + s];
            __syncthreads();
        }
        if (tid == 0) { if (q < NZ) srms[q] = red[0]; else scnt = red[0]; }
        __syncthreads();
    }
    if (tid < NZ) srms[tid] = sqrtf(srms[tid] / scnt) + 1e-8f;
    __syncthreads();
    for (int pix = tid; pix < KK; pix += 256) {
        #pragma unroll
        for (int z = 0; z < NZ; ++z)
            basis[z * KK + pix] = basis[z * KK + pix] / srms[z];
    }
}

// 121 unique coords (batch-tiled in reference), one block of 64 per coord.
__global__ void k_mlp(const float* __restrict__ w1, const float* __restrict__ b1,
                      const float* __restrict__ w2, const float* __restrict__ b2,
                      const float* __restrict__ w3, const float* __restrict__ b3,
                      float* __restrict__ ws) {
    __shared__ float h1[HID], h2[HID];
    int n = blockIdx.x, t = threadIdx.x;
    int a = n / NHW, bw = n - a * NHW;
    float gy = (float)((((double)(a * 64)  + 64.0) / 768.0) * 2.0 - 1.0);
    float gx = (float)((((double)(bw * 64) + 64.0) / 768.0) * 2.0 - 1.0);
    h1[t] = tanhf(gy * w1[t] + gx * w1[HID + t] + b1[t]);
    __syncthreads();
    float acc2 = b2[t];
    for (int k = 0; k < HID; ++k) acc2 += h1[k] * w2[k * HID + t];
    h2[t] = tanhf(acc2);
    __syncthreads();
    if (t < NZ) {
        float acc3 = b3[t];
        for (int k = 0; k < HID; ++k) acc3 += h2[k] * w3[k * NZ + t];
        ws[COEF_OFF + n * NZ + t] = acc3;
    }
}

// One block per (n,c): phase -> field -> 31-pt row DFT -> col DFT -> |F|^2,
// normalize; fftshift+flip folded; store TRANSPOSED: Kt[v*31+u] so that per
// v the u-taps are contiguous for s_load vectorization in k_conv.
__global__ void k_psf(float* __restrict__ ws) {
    __shared__ float fre[KK], fim[KK], gre[KK], gim[KK], sS[KK];
    __shared__ float twc[KS], tws[KS], cf[NZ], red[128];
    int blk = blockIdx.x;
    int n = blk / 3, c = blk - n * 3;
    int tid = threadIdx.x;
    const float* basis = ws + BASIS_OFF;
    const float* mask  = ws + MASK_OFF;
    if (tid < NZ) cf[tid] = ws[COEF_OFF + n * NZ + tid];
    if (tid < KS) {
        float ang = -6.283185307179586f * (float)tid / 31.0f;
        float s, co;
        sincosf(ang, &s, &co);
        twc[tid] = co; tws[tid] = s;
    }
    const float wl = (c == 0) ? (0.53f / 0.61f) : ((c == 1) ? 1.0f : (0.53f / 0.47f));
    __syncthreads();
    for (int pix = tid; pix < KK; pix += 128) {
        float ph = 0.0f;
        #pragma unroll
        for (int z = 0; z < NZ; ++z) ph += cf[z] * basis[z * KK + pix];
        float ang = 6.283185307179586f * (wl * ph);
        float s, co;
        sincosf(ang, &s, &co);
        float m = mask[pix];
        fre[pix] = m * co;
        fim[pix] = m * s;
    }
    __syncthreads();
    for (int pix = tid; pix < KK; pix += 128) {
        int i = pix / 31, q = pix - i * 31;
        float ar = 0.0f, ai = 0.0f;
        int m = 0;
        const float* br = &fre[i * 31];
        const float* bi = &fim[i * 31];
        #pragma unroll
        for (int j = 0; j < 31; ++j) {
            float tc = twc[m], ts = tws[m];
            float xr = br[j], xi = bi[j];
            ar += xr * tc - xi * ts;
            ai += xr * ts + xi * tc;
            m += q; if (m >= 31) m -= 31;
        }
        gre[pix] = ar; gim[pix] = ai;
    }
    __syncthreads();
    float lsum = 0.0f;
    for (int pix = tid; pix < KK; pix += 128) {
        int p = pix / 31, q = pix - p * 31;
        float ar = 0.0f, ai = 0.0f;
        int m = 0;
        #pragma unroll
        for (int i2 = 0; i2 < 31; ++i2) {
            float tc = twc[m], ts = tws[m];
            float xr = gre[i2 * 31 + q], xi = gim[i2 * 31 + q];
            ar += xr * tc - xi * ts;
            ai += xr * ts + xi * tc;
            m += p; if (m >= 31) m -= 31;
        }
        float sv = ar * ar + ai * ai;
        sS[pix] = sv;
        lsum += sv;
    }
    red[tid] = lsum;
    __syncthreads();
    for (int s = 64; s > 0; s >>= 1) {
        if (tid < s) red[tid] += red[tid + s];
        __syncthreads();
    }
    float tot = red[0] + EPSF;
    float* kern = ws + KERN_OFF + (n * 3 + c) * KK;
    for (int pix = tid; pix < KK; pix += 128) {
        int u = pix / 31, v = pix - u * 31;
        int iu = 15 - u; if (iu < 0) iu += 31;
        int iv = 15 - v; if (iv < 0) iv += 31;
        kern[v * 31 + u] = sS[iu * 31 + iv] / tot;   // transposed store
    }
}

// Hot kernel, R4: packed fp32 + scalar-pipe taps + paired LDS reads.
// Block = 128 thr (2 waves), tile 64 rows x 64 cols; grid.y: 2 row-blks x 2 col-blks.
// Wave = 32 rows x 64 cols; lane owns 1 col; float2 packs row pair (t, t+16).
// LDS slab stride 128 dwords so the (s, s+16) row pair is 32*64 dwords apart
// -> single ds_read2st64_b32 per pair, lanes stride-1 (conflict-free).
// Taps Kt[v*31+u] read wave-uniform from global -> s_load (scalar cache),
// zero LDS broadcasts. Inner op: v_pk_fma_f32; tap broadcast into a VGPR
// pair (v_pk_fma src1 must be a 64-bit operand — single SGPR was the R3
// compile failure). Per v-step per wave: 46 LDS instrs / 496 pk-FMAs.
__global__ __launch_bounds__(128) void k_conv(const float* __restrict__ ws,
                                              float* __restrict__ out) {
    __shared__ float sP[94 * 128];
    int unit = blockIdx.x;
    int rowblk = blockIdx.y >> 1;
    int colblk = blockIdx.y & 1;
    int bn = unit / 3, c = unit - bn * 3;
    int b = bn / NN, n = bn - b * NN;
    int a = n / NHW, bw = n - a * NHW;
    int tid = threadIdx.x;
    const float* ktr = ws + KERN_OFF + (n * 3 + c) * KK;  // transposed taps
    const float* xl = ws + XLIN_OFF + (b * 3 + c) * (HH * HH);
    int prow0 = rowblk * 64;   // patch-row base of this block's outputs
    int pcol0 = colblk * 64;   // patch-col base
    // stage rows prow0-15..prow0+78, cols pcol0-15..pcol0+78 (zero-padded)
    for (int idx = tid; idx < 94 * 94; idx += 128) {
        int s = idx / 94, pc = idx - s * 94;
        int pi = prow0 + s - 15;
        int pj = pcol0 + pc - 15;
        float v = 0.0f;
        if (pi >= 0 && pi < 128 && pj >= 0 && pj < 128)
            v = xl[(a * 64 + pi) * HH + (bw * 64 + pj)];
        sP[s * 128 + pc] = v;
    }
    __syncthreads();
    int wave = tid >> 6, lane = tid & 63;
    int wr = wave * 32;           // wave's row offset within the 64-row tile
    v2f acc[16];
    v2f zz = {0.0f, 0.0f};
    #pragma unroll
    for (int t = 0; t < 16; ++t) acc[t] = zz;
    const float* pbase = sP + wr * 128 + lane;
    #pragma unroll 1
    for (int v = 0; v < 31; ++v) {
        const float* pv = pbase + v;      // v folded into base reg -> offsets are
        v2f w2[46];                       // pure multiples of 64 dwords (st64-able)
        #pragma unroll
        for (int s = 0; s < 46; ++s) {
            w2[s].x = pv[s * 128];          // row wr+s
            w2[s].y = pv[s * 128 + 2048];   // row wr+s+16 (16*128 dwords)
        }
        const float* kvp = ktr + v * 31;
        #pragma unroll
        for (int u = 0; u < 31; ++u) {
            float kv = kvp[u];              // wave-uniform -> s_load
            v2f kv2;
            kv2.x = kv; kv2.y = kv;         // 64-bit VGPR-pair operand
            #pragma unroll
            for (int t = 0; t < 16; ++t) {
                // acc.lo += w.lo*kv ; acc.hi += w.hi*kv
                asm("v_pk_fma_f32 %0, %1, %2, %0"
                    : "+v"(acc[t])
                    : "v"(w2[u + t]), "v"(kv2));
            }
        }
    }
    float wcol = hann_f(pcol0 + lane);
    float* ob = out + (b * 3 + c) * (HH * HH) + (a * 64) * HH + bw * 64 + pcol0 + lane;
    #pragma unroll
    for (int t = 0; t < 16; ++t) {
        int i = prow0 + wr + t;
        atomicAdd(ob + i * HH, acc[t].x * hann_f(i) * wcol);
        int i2 = i + 16;
        atomicAdd(ob + i2 * HH, acc[t].y * hann_f(i2) * wcol);
    }
}

// Overlap-add normalization (norm is separable: sh[y]*sw[x]) + inverse gamma.
__global__ void k_final(float* __restrict__ out, const float* __restrict__ gp, int ntot) {
    float ig = 1.0f / (*gp);
    for (int idx = blockIdx.x * blockDim.x + threadIdx.x; idx < ntot;
         idx += gridDim.x * blockDim.x) {
        int x = idx % HH;
        int y = (idx / HH) % HH;
        int ay = y >> 6, ry = y - (ay << 6);
        float sh = 0.0f;
        if (ay <= 10) sh += hann_f(ry);
        if (ay >= 1)  sh += hann_f(ry + 64);
        int ax = x >> 6, rx = x - (ax << 6);
        float sw = 0.0f;
        if (ax <= 10) sw += hann_f(rx);
        if (ax >= 1)  sw += hann_f(rx + 64);
        float v = out[idx] / (sh * sw + EPSF);
        out[idx] = powf(fmaxf(v, 0.0f) + EPSF, ig);
    }
}

extern "C" void kernel_launch(void* const* d_in, const int* in_sizes, int n_in,
                              void* d_out, int out_size, void* d_ws, size_t ws_size,
                              hipStream_t stream) {
    const float* x  = (const float*)d_in[0];
    const float* w1 = (const float*)d_in[1];
    const float* b1 = (const float*)d_in[2];
    const float* w2 = (const float*)d_in[3];
    const float* b2 = (const float*)d_in[4];
    const float* w3 = (const float*)d_in[5];
    const float* b3 = (const float*)d_in[6];
    const float* gp = (const float*)d_in[7];
    float* out = (float*)d_out;
    float* ws  = (float*)d_ws;

    hipMemsetAsync(d_out, 0, (size_t)out_size * sizeof(float), stream);
    int ntot = NB * NC * HH * HH;
    k_pow<<<4096, 256, 0, stream>>>(x, gp, ws + XLIN_OFF, ntot);
    k_basis<<<1, 256, 0, stream>>>(ws);
    k_mlp<<<NN, 64, 0, stream>>>(w1, b1, w2, b2, w3, b3, ws);
    k_psf<<<NN * NC, 128, 0, stream>>>(ws);
    dim3 cg(NB * NN * NC, 4);
    k_conv<<<cg, 128, 0, stream>>>(ws, out);
    k_final<<<4096, 256, 0, stream>>>(out, gp, ntot);
}

// Round 6
// 630.771 us; speedup vs baseline: 1.4834x; 1.4834x over previous
//
#include <hip/hip_runtime.h>
#include <math.h>

#define EPSF 1e-6f
#define NB   4
#define NC   3
#define HH   768
#define KS   31
#define KK   961
#define NHW  11
#define NN   121
#define NZ   14
#define HID  64

// workspace layout (float offsets)
#define XLIN_OFF  0
#define XLIN_SZ   (NB*NC*HH*HH)            // 7,077,888
#define BASIS_OFF (XLIN_OFF + XLIN_SZ)
#define MASK_OFF  (BASIS_OFF + 13456)      // basis needs 14*961=13454
#define COEF_OFF  (MASK_OFF + 964)         // mask needs 961
#define KERN_OFF  (COEF_OFF + 1696)        // packed f16 taps: 512 dwords/unit
// kern needs 363*512 = 185,856 -> total ~29.2 MB

typedef _Float16 h2 __attribute__((ext_vector_type(2)));

__device__ __forceinline__ unsigned pack_h2(float a, float b) {
    // cvt_pkrtz returns __fp16x2; round-trip through bit_cast to unsigned.
    return __builtin_bit_cast(unsigned, __builtin_amdgcn_cvt_pkrtz(a, b));
}

__device__ __forceinline__ float hann_f(int p) {
    return 0.5f * (1.0f - cosf(6.283185307179586f * (float)p / 128.0f));
}

__global__ void k_pow(const float* __restrict__ x, const float* __restrict__ gp,
                      float* __restrict__ y, int n) {
    float g = *gp;
    for (int i = blockIdx.x * blockDim.x + threadIdx.x; i < n; i += gridDim.x * blockDim.x)
        y[i] = powf(fmaxf(x[i], 0.0f) + EPSF, g);
}

// Zernike-like polynomial basis, bit-exact mask vs numpy linspace semantics.
__global__ void k_basis(float* __restrict__ ws) {
    __shared__ float red[256];
    __shared__ float srms[NZ];
    __shared__ float scnt;
    float* basis = ws + BASIS_OFF;
    float* mask  = ws + MASK_OFF;
    int tid = threadIdx.x;
    double lsq[NZ];
    #pragma unroll
    for (int z = 0; z < NZ; ++z) lsq[z] = 0.0;
    double lcnt = 0.0;
    for (int pix = tid; pix < KK; pix += 256) {
        int i = pix / 31, j = pix - i * 31;
        double x = (j == 30) ? 1.0 : (-1.0 + (double)j * (2.0 / 30.0));
        double y = (i == 30) ? 1.0 : (-1.0 + (double)i * (2.0 / 30.0));
        double r2 = x * x + y * y;
        float m = (r2 <= 1.0) ? 1.0f : 0.0f;
        mask[pix] = m;
        lcnt += (double)m;
        #pragma unroll
        for (int deg = 1; deg <= 4; ++deg) {
            #pragma unroll
            for (int ii = 0; ii <= deg; ++ii) {
                const int z = deg * (deg + 1) / 2 - 1 + ii;
                double px = 1.0, py = 1.0;
                #pragma unroll
                for (int t = 0; t < deg - ii; ++t) px *= x;
                #pragma unroll
                for (int t = 0; t < ii; ++t) py *= y;
                float bf = (float)(px * py) * m;
                basis[z * KK + pix] = bf;
                lsq[z] += (double)bf * (double)bf;
            }
        }
    }
    for (int q = 0; q < NZ + 1; ++q) {
        red[tid] = (q < NZ) ? (float)lsq[q] : (float)lcnt;
        __syncthreads();
        for (int s = 128; s > 0; s >>= 1) {
            if (tid < s) red[tid] += red[tid + s];
            __syncthreads();
        }
        if (tid == 0) { if (q < NZ) srms[q] = red[0]; else scnt = red[0]; }
        __syncthreads();
    }
    if (tid < NZ) srms[tid] = sqrtf(srms[tid] / scnt) + 1e-8f;
    __syncthreads();
    for (int pix = tid; pix < KK; pix += 256) {
        #pragma unroll
        for (int z = 0; z < NZ; ++z)
            basis[z * KK + pix] = basis[z * KK + pix] / srms[z];
    }
}

// 121 unique coords (batch-tiled in reference), one block of 64 per coord.
__global__ void k_mlp(const float* __restrict__ w1, const float* __restrict__ b1,
                      const float* __restrict__ w2, const float* __restrict__ b2,
                      const float* __restrict__ w3, const float* __restrict__ b3,
                      float* __restrict__ ws) {
    __shared__ float h1[HID], h2v[HID];
    int n = blockIdx.x, t = threadIdx.x;
    int a = n / NHW, bw = n - a * NHW;
    float gy = (float)((((double)(a * 64)  + 64.0) / 768.0) * 2.0 - 1.0);
    float gx = (float)((((double)(bw * 64) + 64.0) / 768.0) * 2.0 - 1.0);
    h1[t] = tanhf(gy * w1[t] + gx * w1[HID + t] + b1[t]);
    __syncthreads();
    float acc2 = b2[t];
    for (int k = 0; k < HID; ++k) acc2 += h1[k] * w2[k * HID + t];
    h2v[t] = tanhf(acc2);
    __syncthreads();
    if (t < NZ) {
        float acc3 = b3[t];
        for (int k = 0; k < HID; ++k) acc3 += h2v[k] * w3[k * NZ + t];
        ws[COEF_OFF + n * NZ + t] = acc3;
    }
}

// One block per (n,c): phase -> field -> 31-pt row DFT -> col DFT -> |F|^2,
// normalize; fftshift+flip folded. Store taps as f16 u-pairs per v:
// kp[v*16+u2] = pack_f16(K[2u2,v], K[2u2+1,v]) with K[31]=0 pad, so k_conv
// can consume them with v_dot2_f32_f16 via wave-uniform scalar loads.
__global__ void k_psf(float* __restrict__ ws) {
    __shared__ float fre[KK], fim[KK], gre[KK], gim[KK], sS[KK];
    __shared__ float twc[KS], tws[KS], cf[NZ], red[128];
    int blk = blockIdx.x;
    int n = blk / 3, c = blk - n * 3;
    int tid = threadIdx.x;
    const float* basis = ws + BASIS_OFF;
    const float* mask  = ws + MASK_OFF;
    if (tid < NZ) cf[tid] = ws[COEF_OFF + n * NZ + tid];
    if (tid < KS) {
        float ang = -6.283185307179586f * (float)tid / 31.0f;
        float s, co;
        sincosf(ang, &s, &co);
        twc[tid] = co; tws[tid] = s;
    }
    const float wl = (c == 0) ? (0.53f / 0.61f) : ((c == 1) ? 1.0f : (0.53f / 0.47f));
    __syncthreads();
    for (int pix = tid; pix < KK; pix += 128) {
        float ph = 0.0f;
        #pragma unroll
        for (int z = 0; z < NZ; ++z) ph += cf[z] * basis[z * KK + pix];
        float ang = 6.283185307179586f * (wl * ph);
        float s, co;
        sincosf(ang, &s, &co);
        float m = mask[pix];
        fre[pix] = m * co;
        fim[pix] = m * s;
    }
    __syncthreads();
    for (int pix = tid; pix < KK; pix += 128) {
        int i = pix / 31, q = pix - i * 31;
        float ar = 0.0f, ai = 0.0f;
        int m = 0;
        const float* br = &fre[i * 31];
        const float* bi = &fim[i * 31];
        #pragma unroll
        for (int j = 0; j < 31; ++j) {
            float tc = twc[m], ts = tws[m];
            float xr = br[j], xi = bi[j];
            ar += xr * tc - xi * ts;
            ai += xr * ts + xi * tc;
            m += q; if (m >= 31) m -= 31;
        }
        gre[pix] = ar; gim[pix] = ai;
    }
    __syncthreads();
    float lsum = 0.0f;
    for (int pix = tid; pix < KK; pix += 128) {
        int p = pix / 31, q = pix - p * 31;
        float ar = 0.0f, ai = 0.0f;
        int m = 0;
        #pragma unroll
        for (int i2 = 0; i2 < 31; ++i2) {
            float tc = twc[m], ts = tws[m];
            float xr = gre[i2 * 31 + q], xi = gim[i2 * 31 + q];
            ar += xr * tc - xi * ts;
            ai += xr * ts + xi * tc;
            m += p; if (m >= 31) m -= 31;
        }
        float sv = ar * ar + ai * ai;
        sS[pix] = sv;
        lsum += sv;
    }
    red[tid] = lsum;
    __syncthreads();
    for (int s = 64; s > 0; s >>= 1) {
        if (tid < s) red[tid] += red[tid + s];
        __syncthreads();
    }
    float tot = red[0] + EPSF;
    unsigned* kp = (unsigned*)(ws + KERN_OFF) + (n * 3 + c) * 512;
    // K[u,v] = sS[((15-u)%31)*31 + (15-v)%31] / tot; pack u-pairs, K[31]=0
    for (int idx = tid; idx < 31 * 16; idx += 128) {
        int v = idx >> 4, u2 = idx & 15;
        int iv = 15 - v; if (iv < 0) iv += 31;
        int u0 = 2 * u2, u1 = u0 + 1;
        int iu0 = 15 - u0; if (iu0 < 0) iu0 += 31;
        float k0 = sS[iu0 * 31 + iv] / tot;
        float k1 = 0.0f;
        if (u1 < 31) {
            int iu1 = 15 - u1; if (iu1 < 0) iu1 += 31;
            k1 = sS[iu1 * 31 + iv] / tot;
        }
        kp[v * 16 + u2] = pack_h2(k0, k1);
    }
}

// Hot kernel, R6 (= R5 theory, compile-fixed): f16 dot2 datapath.
// Block = 256 thr (4 waves), tile 32 rows x 128 cols; grid (1452, 4 row-blks).
// Wave = 16 rows x 64 cols; lane owns one output column.
// LDS slab: row-pair-packed f16, column-major: sP2[col*33 + rp] holds
// (P[row0-15+2rp, col-15], P[row0-15+2rp+1, col-15]) as f16x2. Stride 33
// (odd) -> lanes conflict-free; per-lane window = 24 contiguous dwords ->
// ds_read2_b32 merging. Taps via wave-uniform s_load (512 dwords/unit).
// Per wave-v-step: 12 LDS + 23 alignbit + 256 v_dot2_f32_f16 (512 MACs).
__global__ __launch_bounds__(256, 4) void k_conv(const float* __restrict__ ws,
                                                 float* __restrict__ out) {
    __shared__ unsigned sP2[158 * 33];   // 20856 B
    int unit = blockIdx.x;
    int rb = blockIdx.y;
    int bn = unit / 3, c = unit - bn * 3;
    int b = bn / NN, n = bn - b * NN;
    int a = n / NHW, bw = n - a * NHW;
    int tid = threadIdx.x;
    const unsigned* kpb = (const unsigned*)(ws + KERN_OFF) + (n * 3 + c) * 512;
    const float* xl = ws + XLIN_OFF + (b * 3 + c) * (HH * HH);
    int row0 = rb * 32;   // output-row base (patch-local)
    // stage: rowpairs rp 0..31 cover patch rows row0-15 .. row0+48 (zero-pad
    // outside [0,128)); cols col 0..157 cover patch cols -15..142.
    for (int idx = tid; idx < 32 * 158; idx += 256) {
        int rp = idx / 158, col = idx - rp * 158;
        int r0 = row0 - 15 + 2 * rp;
        int pj = col - 15;
        float f0 = 0.0f, f1 = 0.0f;
        if ((unsigned)pj < 128u) {
            const float* cbase = xl + (bw * 64 + pj);
            if ((unsigned)r0 < 128u)       f0 = cbase[(a * 64 + r0) * HH];
            if ((unsigned)(r0 + 1) < 128u) f1 = cbase[(a * 64 + r0 + 1) * HH];
        }
        sP2[col * 33 + rp] = pack_h2(f0, f1);
    }
    __syncthreads();
    int wave = tid >> 6, lane = tid & 63;
    int wr = (wave >> 1) * 16;    // wave's output-row offset within block (0|16)
    int c0 = (wave & 1) * 64;     // wave's column base (0|64)
    int wrp = wr >> 1;            // window base rowpair (0|8)
    float acc[16];
    #pragma unroll
    for (int r = 0; r < 16; ++r) acc[r] = 0.0f;
    #pragma unroll 1
    for (int v = 0; v < 31; ++v) {
        const unsigned* pv = sP2 + (c0 + lane + v) * 33 + wrp;
        unsigned WA[24];
        #pragma unroll
        for (int s = 0; s < 24; ++s) WA[s] = pv[s];
        unsigned WB[23];
        #pragma unroll
        for (int s = 0; s < 23; ++s)
            WB[s] = __builtin_amdgcn_alignbit(WA[s + 1], WA[s], 16);
        const unsigned* kp = kpb + v * 16;
        #pragma unroll
        for (int u2 = 0; u2 < 16; ++u2) {
            h2 k2 = __builtin_bit_cast(h2, kp[u2]);   // wave-uniform -> s_load
            #pragma unroll
            for (int q = 0; q < 8; ++q) {
                acc[2 * q] = __builtin_amdgcn_fdot2(
                    __builtin_bit_cast(h2, WA[q + u2]), k2, acc[2 * q], false);
                acc[2 * q + 1] = __builtin_amdgcn_fdot2(
                    __builtin_bit_cast(h2, WB[q + u2 > 22 ? 22 : q + u2]), k2,
                    acc[2 * q + 1], false);
            }
        }
    }
    float wcol = hann_f(c0 + lane);
    float* ob = out + (b * 3 + c) * (HH * HH) + (a * 64) * HH + bw * 64 + c0 + lane;
    #pragma unroll
    for (int r = 0; r < 16; ++r) {
        int i = row0 + wr + r;
        atomicAdd(ob + i * HH, acc[r] * hann_f(i) * wcol);
    }
}

// Overlap-add normalization (norm is separable: sh[y]*sw[x]) + inverse gamma.
__global__ void k_final(float* __restrict__ out, const float* __restrict__ gp, int ntot) {
    float ig = 1.0f / (*gp);
    for (int idx = blockIdx.x * blockDim.x + threadIdx.x; idx < ntot;
         idx += gridDim.x * blockDim.x) {
        int x = idx % HH;
        int y = (idx / HH) % HH;
        int ay = y >> 6, ry = y - (ay << 6);
        float sh = 0.0f;
        if (ay <= 10) sh += hann_f(ry);
        if (ay >= 1)  sh += hann_f(ry + 64);
        int ax = x >> 6, rx = x - (ax << 6);
        float sw = 0.0f;
        if (ax <= 10) sw += hann_f(rx);
        if (ax >= 1)  sw += hann_f(rx + 64);
        float v = out[idx] / (sh * sw + EPSF);
        out[idx] = powf(fmaxf(v, 0.0f) + EPSF, ig);
    }
}

extern "C" void kernel_launch(void* const* d_in, const int* in_sizes, int n_in,
                              void* d_out, int out_size, void* d_ws, size_t ws_size,
                              hipStream_t stream) {
    const float* x  = (const float*)d_in[0];
    const float* w1 = (const float*)d_in[1];
    const float* b1 = (const float*)d_in[2];
    const float* w2 = (const float*)d_in[3];
    const float* b2 = (const float*)d_in[4];
    const float* w3 = (const float*)d_in[5];
    const float* b3 = (const float*)d_in[6];
    const float* gp = (const float*)d_in[7];
    float* out = (float*)d_out;
    float* ws  = (float*)d_ws;

    (void)hipMemsetAsync(d_out, 0, (size_t)out_size * sizeof(float), stream);
    int ntot = NB * NC * HH * HH;
    k_pow<<<4096, 256, 0, stream>>>(x, gp, ws + XLIN_OFF, ntot);
    k_basis<<<1, 256, 0, stream>>>(ws);
    k_mlp<<<NN, 64, 0, stream>>>(w1, b1, w2, b2, w3, b3, ws);
    k_psf<<<NN * NC, 128, 0, stream>>>(ws);
    dim3 cg(NB * NN * NC, 4);
    k_conv<<<cg, 256, 0, stream>>>(ws, out);
    k_final<<<4096, 256, 0, stream>>>(out, gp, ntot);
}

// Round 7
// 630.337 us; speedup vs baseline: 1.4844x; 1.0007x over previous
//
#include <hip/hip_runtime.h>
#include <math.h>

#define EPSF 1e-6f
#define NB   4
#define NC   3
#define HH   768
#define KS   31
#define KK   961
#define NHW  11
#define NN   121
#define NZ   14
#define HID  64

// workspace layout (float offsets)
#define XLIN_OFF  0
#define XLIN_SZ   (NB*NC*HH*HH)            // 7,077,888
#define BASIS_OFF (XLIN_OFF + XLIN_SZ)
#define MASK_OFF  (BASIS_OFF + 13456)      // basis needs 14*961=13454
#define COEF_OFF  (MASK_OFF + 964)         // mask needs 961
#define KERN_OFF  (COEF_OFF + 1696)        // packed f16 taps: 512 dwords/unit
// kern needs 363*512 = 185,856 -> total ~29.2 MB

typedef _Float16 h2 __attribute__((ext_vector_type(2)));

__device__ __forceinline__ unsigned pack_h2(float a, float b) {
    // cvt_pkrtz returns __fp16x2; round-trip through bit_cast to unsigned.
    return __builtin_bit_cast(unsigned, __builtin_amdgcn_cvt_pkrtz(a, b));
}

__device__ __forceinline__ float hann_f(int p) {
    return 0.5f * (1.0f - cosf(6.283185307179586f * (float)p / 128.0f));
}

__global__ void k_pow(const float* __restrict__ x, const float* __restrict__ gp,
                      float* __restrict__ y, int n) {
    float g = *gp;
    for (int i = blockIdx.x * blockDim.x + threadIdx.x; i < n; i += gridDim.x * blockDim.x)
        y[i] = powf(fmaxf(x[i], 0.0f) + EPSF, g);
}

// Zernike-like polynomial basis, bit-exact mask vs numpy linspace semantics.
__global__ void k_basis(float* __restrict__ ws) {
    __shared__ float red[256];
    __shared__ float srms[NZ];
    __shared__ float scnt;
    float* basis = ws + BASIS_OFF;
    float* mask  = ws + MASK_OFF;
    int tid = threadIdx.x;
    double lsq[NZ];
    #pragma unroll
    for (int z = 0; z < NZ; ++z) lsq[z] = 0.0;
    double lcnt = 0.0;
    for (int pix = tid; pix < KK; pix += 256) {
        int i = pix / 31, j = pix - i * 31;
        double x = (j == 30) ? 1.0 : (-1.0 + (double)j * (2.0 / 30.0));
        double y = (i == 30) ? 1.0 : (-1.0 + (double)i * (2.0 / 30.0));
        double r2 = x * x + y * y;
        float m = (r2 <= 1.0) ? 1.0f : 0.0f;
        mask[pix] = m;
        lcnt += (double)m;
        #pragma unroll
        for (int deg = 1; deg <= 4; ++deg) {
            #pragma unroll
            for (int ii = 0; ii <= deg; ++ii) {
                const int z = deg * (deg + 1) / 2 - 1 + ii;
                double px = 1.0, py = 1.0;
                #pragma unroll
                for (int t = 0; t < deg - ii; ++t) px *= x;
                #pragma unroll
                for (int t = 0; t < ii; ++t) py *= y;
                float bf = (float)(px * py) * m;
                basis[z * KK + pix] = bf;
                lsq[z] += (double)bf * (double)bf;
            }
        }
    }
    for (int q = 0; q < NZ + 1; ++q) {
        red[tid] = (q < NZ) ? (float)lsq[q] : (float)lcnt;
        __syncthreads();
        for (int s = 128; s > 0; s >>= 1) {
            if (tid < s) red[tid] += red[tid + s];
            __syncthreads();
        }
        if (tid == 0) { if (q < NZ) srms[q] = red[0]; else scnt = red[0]; }
        __syncthreads();
    }
    if (tid < NZ) srms[tid] = sqrtf(srms[tid] / scnt) + 1e-8f;
    __syncthreads();
    for (int pix = tid; pix < KK; pix += 256) {
        #pragma unroll
        for (int z = 0; z < NZ; ++z)
            basis[z * KK + pix] = basis[z * KK + pix] / srms[z];
    }
}

// 121 unique coords (batch-tiled in reference), one block of 64 per coord.
__global__ void k_mlp(const float* __restrict__ w1, const float* __restrict__ b1,
                      const float* __restrict__ w2, const float* __restrict__ b2,
                      const float* __restrict__ w3, const float* __restrict__ b3,
                      float* __restrict__ ws) {
    __shared__ float h1[HID], h2v[HID];
    int n = blockIdx.x, t = threadIdx.x;
    int a = n / NHW, bw = n - a * NHW;
    float gy = (float)((((double)(a * 64)  + 64.0) / 768.0) * 2.0 - 1.0);
    float gx = (float)((((double)(bw * 64) + 64.0) / 768.0) * 2.0 - 1.0);
    h1[t] = tanhf(gy * w1[t] + gx * w1[HID + t] + b1[t]);
    __syncthreads();
    float acc2 = b2[t];
    for (int k = 0; k < HID; ++k) acc2 += h1[k] * w2[k * HID + t];
    h2v[t] = tanhf(acc2);
    __syncthreads();
    if (t < NZ) {
        float acc3 = b3[t];
        for (int k = 0; k < HID; ++k) acc3 += h2v[k] * w3[k * NZ + t];
        ws[COEF_OFF + n * NZ + t] = acc3;
    }
}

// One block per (n,c): phase -> field -> 31-pt row DFT -> col DFT -> |F|^2,
// normalize; fftshift+flip folded. Store taps as f16 u-pairs per v:
// kp[v*16+u2] = pack_f16(K[2u2,v], K[2u2+1,v]) with K[31]=0 pad, so k_conv
// can consume them with v_dot2_f32_f16 via wave-uniform scalar loads.
__global__ void k_psf(float* __restrict__ ws) {
    __shared__ float fre[KK], fim[KK], gre[KK], gim[KK], sS[KK];
    __shared__ float twc[KS], tws[KS], cf[NZ], red[128];
    int blk = blockIdx.x;
    int n = blk / 3, c = blk - n * 3;
    int tid = threadIdx.x;
    const float* basis = ws + BASIS_OFF;
    const float* mask  = ws + MASK_OFF;
    if (tid < NZ) cf[tid] = ws[COEF_OFF + n * NZ + tid];
    if (tid < KS) {
        float ang = -6.283185307179586f * (float)tid / 31.0f;
        float s, co;
        sincosf(ang, &s, &co);
        twc[tid] = co; tws[tid] = s;
    }
    const float wl = (c == 0) ? (0.53f / 0.61f) : ((c == 1) ? 1.0f : (0.53f / 0.47f));
    __syncthreads();
    for (int pix = tid; pix < KK; pix += 128) {
        float ph = 0.0f;
        #pragma unroll
        for (int z = 0; z < NZ; ++z) ph += cf[z] * basis[z * KK + pix];
        float ang = 6.283185307179586f * (wl * ph);
        float s, co;
        sincosf(ang, &s, &co);
        float m = mask[pix];
        fre[pix] = m * co;
        fim[pix] = m * s;
    }
    __syncthreads();
    for (int pix = tid; pix < KK; pix += 128) {
        int i = pix / 31, q = pix - i * 31;
        float ar = 0.0f, ai = 0.0f;
        int m = 0;
        const float* br = &fre[i * 31];
        const float* bi = &fim[i * 31];
        #pragma unroll
        for (int j = 0; j < 31; ++j) {
            float tc = twc[m], ts = tws[m];
            float xr = br[j], xi = bi[j];
            ar += xr * tc - xi * ts;
            ai += xr * ts + xi * tc;
            m += q; if (m >= 31) m -= 31;
        }
        gre[pix] = ar; gim[pix] = ai;
    }
    __syncthreads();
    float lsum = 0.0f;
    for (int pix = tid; pix < KK; pix += 128) {
        int p = pix / 31, q = pix - p * 31;
        float ar = 0.0f, ai = 0.0f;
        int m = 0;
        #pragma unroll
        for (int i2 = 0; i2 < 31; ++i2) {
            float tc = twc[m], ts = tws[m];
            float xr = gre[i2 * 31 + q], xi = gim[i2 * 31 + q];
            ar += xr * tc - xi * ts;
            ai += xr * ts + xi * tc;
            m += p; if (m >= 31) m -= 31;
        }
        float sv = ar * ar + ai * ai;
        sS[pix] = sv;
        lsum += sv;
    }
    red[tid] = lsum;
    __syncthreads();
    for (int s = 64; s > 0; s >>= 1) {
        if (tid < s) red[tid] += red[tid + s];
        __syncthreads();
    }
    float tot = red[0] + EPSF;
    unsigned* kp = (unsigned*)(ws + KERN_OFF) + (n * 3 + c) * 512;
    // K[u,v] = sS[((15-u)%31)*31 + (15-v)%31] / tot; pack u-pairs, K[31]=0
    for (int idx = tid; idx < 31 * 16; idx += 128) {
        int v = idx >> 4, u2 = idx & 15;
        int iv = 15 - v; if (iv < 0) iv += 31;
        int u0 = 2 * u2, u1 = u0 + 1;
        int iu0 = 15 - u0; if (iu0 < 0) iu0 += 31;
        float k0 = sS[iu0 * 31 + iv] / tot;
        float k1 = 0.0f;
        if (u1 < 31) {
            int iu1 = 15 - u1; if (iu1 < 0) iu1 += 31;
            k1 = sS[iu1 * 31 + iv] / tot;
        }
        kp[v * 16 + u2] = pack_h2(k0, k1);
    }
}

// Hot kernel, R7: R6 structure with the dead index-clamp removed so SROA can
// promote WA/WB to VGPRs (R6 compiled to VGPR=36 -> arrays demoted, ~2.4x
// VALU inflation). Indices q+u2 <= 22 = last WB slot, always in bounds.
// Per wave-v-step: 12 merged LDS reads + 23 alignbit + 256 v_dot2_f32_f16.
__global__ __launch_bounds__(256, 4) void k_conv(const float* __restrict__ ws,
                                                 float* __restrict__ out) {
    __shared__ unsigned sP2[158 * 33];   // 20856 B
    int unit = blockIdx.x;
    int rb = blockIdx.y;
    int bn = unit / 3, c = unit - bn * 3;
    int b = bn / NN, n = bn - b * NN;
    int a = n / NHW, bw = n - a * NHW;
    int tid = threadIdx.x;
    const unsigned* kpb = (const unsigned*)(ws + KERN_OFF) + (n * 3 + c) * 512;
    const float* xl = ws + XLIN_OFF + (b * 3 + c) * (HH * HH);
    int row0 = rb * 32;   // output-row base (patch-local)
    // stage: rowpairs rp 0..31 cover patch rows row0-15 .. row0+48 (zero-pad
    // outside [0,128)); cols col 0..157 cover patch cols -15..142.
    for (int idx = tid; idx < 32 * 158; idx += 256) {
        int rp = idx / 158, col = idx - rp * 158;
        int r0 = row0 - 15 + 2 * rp;
        int pj = col - 15;
        float f0 = 0.0f, f1 = 0.0f;
        if ((unsigned)pj < 128u) {
            const float* cbase = xl + (bw * 64 + pj);
            if ((unsigned)r0 < 128u)       f0 = cbase[(a * 64 + r0) * HH];
            if ((unsigned)(r0 + 1) < 128u) f1 = cbase[(a * 64 + r0 + 1) * HH];
        }
        sP2[col * 33 + rp] = pack_h2(f0, f1);
    }
    __syncthreads();
    int wave = tid >> 6, lane = tid & 63;
    int wr = (wave >> 1) * 16;    // wave's output-row offset within block (0|16)
    int c0 = (wave & 1) * 64;     // wave's column base (0|64)
    int wrp = wr >> 1;            // window base rowpair (0|8)
    float acc[16];
    #pragma unroll
    for (int r = 0; r < 16; ++r) acc[r] = 0.0f;
    #pragma unroll 1
    for (int v = 0; v < 31; ++v) {
        const unsigned* pv = sP2 + (c0 + lane + v) * 33 + wrp;
        unsigned WA[24];
        #pragma unroll
        for (int s = 0; s < 24; ++s) WA[s] = pv[s];
        unsigned WB[23];
        #pragma unroll
        for (int s = 0; s < 23; ++s)
            WB[s] = __builtin_amdgcn_alignbit(WA[s + 1], WA[s], 16);
        const unsigned* kp = kpb + v * 16;
        #pragma unroll
        for (int u2 = 0; u2 < 16; ++u2) {
            h2 k2 = __builtin_bit_cast(h2, kp[u2]);   // wave-uniform -> s_load
            #pragma unroll
            for (int q = 0; q < 8; ++q) {
                acc[2 * q] = __builtin_amdgcn_fdot2(
                    __builtin_bit_cast(h2, WA[q + u2]), k2, acc[2 * q], false);
                acc[2 * q + 1] = __builtin_amdgcn_fdot2(
                    __builtin_bit_cast(h2, WB[q + u2]), k2, acc[2 * q + 1], false);
            }
        }
    }
    float wcol = hann_f(c0 + lane);
    float* ob = out + (b * 3 + c) * (HH * HH) + (a * 64) * HH + bw * 64 + c0 + lane;
    #pragma unroll
    for (int r = 0; r < 16; ++r) {
        int i = row0 + wr + r;
        atomicAdd(ob + i * HH, acc[r] * hann_f(i) * wcol);
    }
}

// Overlap-add normalization (norm is separable: sh[y]*sw[x]) + inverse gamma.
__global__ void k_final(float* __restrict__ out, const float* __restrict__ gp, int ntot) {
    float ig = 1.0f / (*gp);
    for (int idx = blockIdx.x * blockDim.x + threadIdx.x; idx < ntot;
         idx += gridDim.x * blockDim.x) {
        int x = idx % HH;
        int y = (idx / HH) % HH;
        int ay = y >> 6, ry = y - (ay << 6);
        float sh = 0.0f;
        if (ay <= 10) sh += hann_f(ry);
        if (ay >= 1)  sh += hann_f(ry + 64);
        int ax = x >> 6, rx = x - (ax << 6);
        float sw = 0.0f;
        if (ax <= 10) sw += hann_f(rx);
        if (ax >= 1)  sw += hann_f(rx + 64);
        float v = out[idx] / (sh * sw + EPSF);
        out[idx] = powf(fmaxf(v, 0.0f) + EPSF, ig);
    }
}

extern "C" void kernel_launch(void* const* d_in, const int* in_sizes, int n_in,
                              void* d_out, int out_size, void* d_ws, size_t ws_size,
                              hipStream_t stream) {
    const float* x  = (const float*)d_in[0];
    const float* w1 = (const float*)d_in[1];
    const float* b1 = (const float*)d_in[2];
    const float* w2 = (const float*)d_in[3];
    const float* b2 = (const float*)d_in[4];
    const float* w3 = (const float*)d_in[5];
    const float* b3 = (const float*)d_in[6];
    const float* gp = (const float*)d_in[7];
    float* out = (float*)d_out;
    float* ws  = (float*)d_ws;

    (void)hipMemsetAsync(d_out, 0, (size_t)out_size * sizeof(float), stream);
    int ntot = NB * NC * HH * HH;
    k_pow<<<4096, 256, 0, stream>>>(x, gp, ws + XLIN_OFF, ntot);
    k_basis<<<1, 256, 0, stream>>>(ws);
    k_mlp<<<NN, 64, 0, stream>>>(w1, b1, w2, b2, w3, b3, ws);
    k_psf<<<NN * NC, 128, 0, stream>>>(ws);
    dim3 cg(NB * NN * NC, 4);
    k_conv<<<cg, 256, 0, stream>>>(ws, out);
    k_final<<<4096, 256, 0, stream>>>(out, gp, ntot);
}

// Round 8
// 424.738 us; speedup vs baseline: 2.2030x; 1.4841x over previous
//
#include <hip/hip_runtime.h>
#include <math.h>

#define EPSF 1e-6f
#define NB   4
#define NC   3
#define HH   768
#define KS   31
#define KK   961
#define NHW  11
#define NN   121
#define NZ   14
#define HID  64

// workspace layout (float offsets). xlin stored as f16 (u16) now.
#define XLIN_OFF  0
#define XLIN_F    3538944                  // 7,077,888 u16 = 3,538,944 floats
#define BASIS_OFF (XLIN_OFF + XLIN_F)
#define MASK_OFF  (BASIS_OFF + 13456)      // basis 14*961=13454
#define COEF_OFF  (MASK_OFF + 964)         // mask 961
#define KERN_OFF  (COEF_OFF + 1696)        // coeffs 121*14=1694
// kernT f32: 363*961 = 348,843 -> total ~15.6 MB

typedef _Float16 h8 __attribute__((ext_vector_type(8)));
typedef float f32x16 __attribute__((ext_vector_type(16)));

__device__ __forceinline__ unsigned pack_h2(float a, float b) {
    return __builtin_bit_cast(unsigned, __builtin_amdgcn_cvt_pkrtz(a, b));
}

__device__ __forceinline__ float hann_f(int p) {
    return 0.5f * (1.0f - cosf(6.283185307179586f * (float)p / 128.0f));
}

__global__ void k_pow(const float* __restrict__ x, const float* __restrict__ gp,
                      unsigned short* __restrict__ y, int n) {
    float g = *gp;
    for (int i = blockIdx.x * blockDim.x + threadIdx.x; i < n; i += gridDim.x * blockDim.x) {
        _Float16 h = (_Float16)powf(fmaxf(x[i], 0.0f) + EPSF, g);
        y[i] = __builtin_bit_cast(unsigned short, h);
    }
}

// Zernike-like polynomial basis, bit-exact mask vs numpy linspace semantics.
__global__ void k_basis(float* __restrict__ ws) {
    __shared__ float red[256];
    __shared__ float srms[NZ];
    __shared__ float scnt;
    float* basis = ws + BASIS_OFF;
    float* mask  = ws + MASK_OFF;
    int tid = threadIdx.x;
    double lsq[NZ];
    #pragma unroll
    for (int z = 0; z < NZ; ++z) lsq[z] = 0.0;
    double lcnt = 0.0;
    for (int pix = tid; pix < KK; pix += 256) {
        int i = pix / 31, j = pix - i * 31;
        double x = (j == 30) ? 1.0 : (-1.0 + (double)j * (2.0 / 30.0));
        double y = (i == 30) ? 1.0 : (-1.0 + (double)i * (2.0 / 30.0));
        double r2 = x * x + y * y;
        float m = (r2 <= 1.0) ? 1.0f : 0.0f;
        mask[pix] = m;
        lcnt += (double)m;
        #pragma unroll
        for (int deg = 1; deg <= 4; ++deg) {
            #pragma unroll
            for (int ii = 0; ii <= deg; ++ii) {
                const int z = deg * (deg + 1) / 2 - 1 + ii;
                double px = 1.0, py = 1.0;
                #pragma unroll
                for (int t = 0; t < deg - ii; ++t) px *= x;
                #pragma unroll
                for (int t = 0; t < ii; ++t) py *= y;
                float bf = (float)(px * py) * m;
                basis[z * KK + pix] = bf;
                lsq[z] += (double)bf * (double)bf;
            }
        }
    }
    for (int q = 0; q < NZ + 1; ++q) {
        red[tid] = (q < NZ) ? (float)lsq[q] : (float)lcnt;
        __syncthreads();
        for (int s = 128; s > 0; s >>= 1) {
            if (tid < s) red[tid] += red[tid + s];
            __syncthreads();
        }
        if (tid == 0) { if (q < NZ) srms[q] = red[0]; else scnt = red[0]; }
        __syncthreads();
    }
    if (tid < NZ) srms[tid] = sqrtf(srms[tid] / scnt) + 1e-8f;
    __syncthreads();
    for (int pix = tid; pix < KK; pix += 256) {
        #pragma unroll
        for (int z = 0; z < NZ; ++z)
            basis[z * KK + pix] = basis[z * KK + pix] / srms[z];
    }
}

// 121 unique coords (batch-tiled in reference), one block of 64 per coord.
__global__ void k_mlp(const float* __restrict__ w1, const float* __restrict__ b1,
                      const float* __restrict__ w2, const float* __restrict__ b2,
                      const float* __restrict__ w3, const float* __restrict__ b3,
                      float* __restrict__ ws) {
    __shared__ float h1[HID], h2v[HID];
    int n = blockIdx.x, t = threadIdx.x;
    int a = n / NHW, bw = n - a * NHW;
    float gy = (float)((((double)(a * 64)  + 64.0) / 768.0) * 2.0 - 1.0);
    float gx = (float)((((double)(bw * 64) + 64.0) / 768.0) * 2.0 - 1.0);
    h1[t] = tanhf(gy * w1[t] + gx * w1[HID + t] + b1[t]);
    __syncthreads();
    float acc2 = b2[t];
    for (int k = 0; k < HID; ++k) acc2 += h1[k] * w2[k * HID + t];
    h2v[t] = tanhf(acc2);
    __syncthreads();
    if (t < NZ) {
        float acc3 = b3[t];
        for (int k = 0; k < HID; ++k) acc3 += h2v[k] * w3[k * NZ + t];
        ws[COEF_OFF + n * NZ + t] = acc3;
    }
}

// One block per (n,c): phase -> field -> 31-pt row DFT -> col DFT -> |F|^2,
// normalize; fftshift+flip folded; store TRANSPOSED f32: kernT[v*31+u].
__global__ void k_psf(float* __restrict__ ws) {
    __shared__ float fre[KK], fim[KK], gre[KK], gim[KK], sS[KK];
    __shared__ float twc[KS], tws[KS], cf[NZ], red[128];
    int blk = blockIdx.x;
    int n = blk / 3, c = blk - n * 3;
    int tid = threadIdx.x;
    const float* basis = ws + BASIS_OFF;
    const float* mask  = ws + MASK_OFF;
    if (tid < NZ) cf[tid] = ws[COEF_OFF + n * NZ + tid];
    if (tid < KS) {
        float ang = -6.283185307179586f * (float)tid / 31.0f;
        float s, co;
        sincosf(ang, &s, &co);
        twc[tid] = co; tws[tid] = s;
    }
    const float wl = (c == 0) ? (0.53f / 0.61f) : ((c == 1) ? 1.0f : (0.53f / 0.47f));
    __syncthreads();
    for (int pix = tid; pix < KK; pix += 128) {
        float ph = 0.0f;
        #pragma unroll
        for (int z = 0; z < NZ; ++z) ph += cf[z] * basis[z * KK + pix];
        float ang = 6.283185307179586f * (wl * ph);
        float s, co;
        sincosf(ang, &s, &co);
        float m = mask[pix];
        fre[pix] = m * co;
        fim[pix] = m * s;
    }
    __syncthreads();
    for (int pix = tid; pix < KK; pix += 128) {
        int i = pix / 31, q = pix - i * 31;
        float ar = 0.0f, ai = 0.0f;
        int m = 0;
        const float* br = &fre[i * 31];
        const float* bi = &fim[i * 31];
        #pragma unroll
        for (int j = 0; j < 31; ++j) {
            float tc = twc[m], ts = tws[m];
            float xr = br[j], xi = bi[j];
            ar += xr * tc - xi * ts;
            ai += xr * ts + xi * tc;
            m += q; if (m >= 31) m -= 31;
        }
        gre[pix] = ar; gim[pix] = ai;
    }
    __syncthreads();
    float lsum = 0.0f;
    for (int pix = tid; pix < KK; pix += 128) {
        int p = pix / 31, q = pix - p * 31;
        float ar = 0.0f, ai = 0.0f;
        int m = 0;
        #pragma unroll
        for (int i2 = 0; i2 < 31; ++i2) {
            float tc = twc[m], ts = tws[m];
            float xr = gre[i2 * 31 + q], xi = gim[i2 * 31 + q];
            ar += xr * tc - xi * ts;
            ai += xr * ts + xi * tc;
            m += p; if (m >= 31) m -= 31;
        }
        float sv = ar * ar + ai * ai;
        sS[pix] = sv;
        lsum += sv;
    }
    red[tid] = lsum;
    __syncthreads();
    for (int s = 64; s > 0; s >>= 1) {
        if (tid < s) red[tid] += red[tid + s];
        __syncthreads();
    }
    float tot = red[0] + EPSF;
    float* kern = ws + KERN_OFF + (n * 3 + c) * KK;
    for (int pix = tid; pix < KK; pix += 128) {
        int u = pix / 31, v = pix - u * 31;
        int iu = 15 - u; if (iu < 0) iu += 31;
        int iv = 15 - v; if (iv < 0) iv += 31;
        kern[v * 31 + u] = sS[iu * 31 + iv] / tot;   // transposed store
    }
}

// Hot kernel, R8: MFMA banded-Toeplitz conv.
// Out[r,j] = sum_v sum_q T_v[r,q] * Ppad[q, j+v], T_v[r,q] = K[q-r, v].
// One block (4 waves) per unit: M=128 (4 mt), N=128 (wave = one 32-col nt),
// K=160 (10 kb of 16); band: valid kb = 2*mt + o, o in [0,4).
// mfma_f32_32x32x16_f16: A[m=lane&31][k=(lane>>5)*8+e], B[k][n=lane&31],
// C/D: col=lane&31, row=(reg&3)+8*(reg>>2)+4*(lane>>5)  [verified m74/m101].
// Slab: f16 column-major, q-stride 164 (328 B: 8B-aligned b64 reads, 2-way
// bank alias only). A-frags built per-lane from padded kernel column in LDS
// (5 ds_read_b32 + parity alignbit). Slab loaded once; 31 v-iters, no syncs.
__global__ __launch_bounds__(256, 2) void k_conv(const float* __restrict__ ws,
                                                 float* __restrict__ out) {
    __shared__ unsigned short sT[158 * 164];   // 51,824 B
    __shared__ unsigned kcp[31 * 52];          // 6,448 B: Kcolpad f16 pairs
    int unit = blockIdx.x;
    int bn = unit / 3, c = unit - bn * 3;
    int b = bn / NN, n = bn - b * NN;
    int a = n / NHW, bw = n - a * NHW;
    int tid = threadIdx.x;
    const float* kernT = ws + KERN_OFF + (n * 3 + c) * KK;   // kernT[v*31+u]
    // Kcolpad: x in [0,104): value K[x-31, v] (else 0), packed as f16 pairs
    for (int idx = tid; idx < 31 * 52; idx += 256) {
        int v = idx / 52, x2 = idx - v * 52;
        int t0 = 2 * x2 - 31, t1 = t0 + 1;
        float k0 = ((unsigned)t0 < 31u) ? kernT[v * 31 + t0] : 0.0f;
        float k1 = ((unsigned)t1 < 31u) ? kernT[v * 31 + t1] : 0.0f;
        kcp[idx] = pack_h2(k0, k1);
    }
    // slab: col-major f16, sT[col*164 + q] = Ppad[q, col] (zero-padded)
    const unsigned short* xlc =
        (const unsigned short*)ws + (size_t)(b * 3 + c) * (HH * HH);
    for (int i = tid; i < 158 * 158; i += 256) {
        int q = i / 158, col = i - q * 158;
        int pi = q - 15, pj = col - 15;
        unsigned short hv = 0;
        if ((unsigned)pi < 128u && (unsigned)pj < 128u)
            hv = xlc[(a * 64 + pi) * HH + bw * 64 + pj];
        sT[col * 164 + q] = hv;
    }
    for (int i = tid; i < 158 * 6; i += 256) {
        int q = 158 + i / 158, col = i % 158;
        sT[col * 164 + q] = 0;
    }
    __syncthreads();
    int lane = tid & 63;
    int wave = tid >> 6;          // = nt
    int nI = lane & 31;           // n (B/C col) and m (A row) index
    int k8 = lane >> 5;           // K-half selector
    int colbase = wave * 32 + nI; // output column
    f32x16 acc[4];
    #pragma unroll
    for (int m = 0; m < 4; ++m) acc[m] = (f32x16)(0.0f);
    #pragma unroll 1
    for (int v = 0; v < 31; ++v) {
        h8 A[4];
        const unsigned* kv = &kcp[v * 52];
        #pragma unroll
        for (int o = 0; o < 4; ++o) {
            int tA = 16 * o + 8 * k8 - nI + 31;   // in [0, 94]
            int d0 = tA >> 1;
            bool odd = (tA & 1) != 0;
            unsigned D0 = kv[d0], D1 = kv[d0 + 1], D2 = kv[d0 + 2],
                     D3 = kv[d0 + 3], D4 = kv[d0 + 4];
            unsigned w0 = odd ? __builtin_amdgcn_alignbit(D1, D0, 16) : D0;
            unsigned w1 = odd ? __builtin_amdgcn_alignbit(D2, D1, 16) : D1;
            unsigned w2 = odd ? __builtin_amdgcn_alignbit(D3, D2, 16) : D2;
            unsigned w3 = odd ? __builtin_amdgcn_alignbit(D4, D3, 16) : D3;
            uint4 u; u.x = w0; u.y = w1; u.z = w2; u.w = w3;
            A[o] = __builtin_bit_cast(h8, u);
        }
        const unsigned short* cb = &sT[(colbase + v) * 164 + k8 * 8];
        #pragma unroll
        for (int kb = 0; kb < 10; ++kb) {
            const uint2* p = (const uint2*)(cb + kb * 16);   // 8B-aligned
            uint2 lo = p[0], hi = p[1];
            uint4 u; u.x = lo.x; u.y = lo.y; u.z = hi.x; u.w = hi.y;
            h8 B = __builtin_bit_cast(h8, u);
            #pragma unroll
            for (int mt = 0; mt < 4; ++mt) {
                int o = kb - 2 * mt;               // compile-time folded
                if (o >= 0 && o < 4)
                    acc[mt] = __builtin_amdgcn_mfma_f32_32x32x16_f16(
                        A[o], B, acc[mt], 0, 0, 0);
            }
        }
    }
    float wcol = hann_f(colbase);
    float* ob = out + (size_t)(b * 3 + c) * (HH * HH) + (size_t)(a * 64) * HH + bw * 64;
    #pragma unroll
    for (int mt = 0; mt < 4; ++mt) {
        #pragma unroll
        for (int reg = 0; reg < 16; ++reg) {
            int r = mt * 32 + (reg & 3) + 8 * (reg >> 2) + 4 * k8;
            atomicAdd(ob + r * HH + colbase, acc[mt][reg] * hann_f(r) * wcol);
        }
    }
}

// Overlap-add normalization (norm is separable: sh[y]*sw[x]) + inverse gamma.
__global__ void k_final(float* __restrict__ out, const float* __restrict__ gp, int ntot) {
    float ig = 1.0f / (*gp);
    for (int idx = blockIdx.x * blockDim.x + threadIdx.x; idx < ntot;
         idx += gridDim.x * blockDim.x) {
        int x = idx % HH;
        int y = (idx / HH) % HH;
        int ay = y >> 6, ry = y - (ay << 6);
        float sh = 0.0f;
        if (ay <= 10) sh += hann_f(ry);
        if (ay >= 1)  sh += hann_f(ry + 64);
        int ax = x >> 6, rx = x - (ax << 6);
        float sw = 0.0f;
        if (ax <= 10) sw += hann_f(rx);
        if (ax >= 1)  sw += hann_f(rx + 64);
        float v = out[idx] / (sh * sw + EPSF);
        out[idx] = powf(fmaxf(v, 0.0f) + EPSF, ig);
    }
}

extern "C" void kernel_launch(void* const* d_in, const int* in_sizes, int n_in,
                              void* d_out, int out_size, void* d_ws, size_t ws_size,
                              hipStream_t stream) {
    const float* x  = (const float*)d_in[0];
    const float* w1 = (const float*)d_in[1];
    const float* b1 = (const float*)d_in[2];
    const float* w2 = (const float*)d_in[3];
    const float* b2 = (const float*)d_in[4];
    const float* w3 = (const float*)d_in[5];
    const float* b3 = (const float*)d_in[6];
    const float* gp = (const float*)d_in[7];
    float* out = (float*)d_out;
    float* ws  = (float*)d_ws;

    (void)hipMemsetAsync(d_out, 0, (size_t)out_size * sizeof(float), stream);
    int ntot = NB * NC * HH * HH;
    k_pow<<<4096, 256, 0, stream>>>(x, gp, (unsigned short*)(ws + XLIN_OFF), ntot);
    k_basis<<<1, 256, 0, stream>>>(ws);
    k_mlp<<<NN, 64, 0, stream>>>(w1, b1, w2, b2, w3, b3, ws);
    k_psf<<<NN * NC, 128, 0, stream>>>(ws);
    k_conv<<<NB * NN * NC, 256, 0, stream>>>(ws, out);
    k_final<<<4096, 256, 0, stream>>>(out, gp, ntot);
}

// Round 9
// 415.635 us; speedup vs baseline: 2.2513x; 1.0219x over previous
//
#include <hip/hip_runtime.h>
#include <math.h>

#define EPSF 1e-6f
#define NB   4
#define NC   3
#define HH   768
#define KS   31
#define KK   961
#define NHW  11
#define NN   121
#define NZ   14
#define HID  64

// workspace layout (float offsets). xlin stored as f16 (u16).
#define XLIN_OFF  0
#define XLIN_F    3538944                  // 7,077,888 u16 = 3,538,944 floats
#define BASIS_OFF (XLIN_OFF + XLIN_F)
#define MASK_OFF  (BASIS_OFF + 13456)      // basis 14*961=13454
#define COEF_OFF  (MASK_OFF + 964)         // mask 961
#define KERN_OFF  (COEF_OFF + 1696)        // parity-packed f16 tap tables
#define KNC_DW    (31 * 106)               // 3286 dwords per (n,c): v x {p0:53,p1:53}
// kern region: 363*3286 dwords = 4.77 MB -> total ws ~19 MB

typedef _Float16 h8 __attribute__((ext_vector_type(8)));
typedef float f32x16 __attribute__((ext_vector_type(16)));
typedef uint4 uint4_u __attribute__((aligned(4)));   // 4B-aligned 16B load

__device__ __forceinline__ unsigned pack_h2(float a, float b) {
    return __builtin_bit_cast(unsigned, __builtin_amdgcn_cvt_pkrtz(a, b));
}

__device__ __forceinline__ float hann_f(int p) {
    return 0.5f * (1.0f - cosf(6.283185307179586f * (float)p / 128.0f));
}

__global__ void k_pow(const float* __restrict__ x, const float* __restrict__ gp,
                      unsigned short* __restrict__ y, int n) {
    float g = *gp;
    for (int i = blockIdx.x * blockDim.x + threadIdx.x; i < n; i += gridDim.x * blockDim.x) {
        _Float16 h = (_Float16)__powf(fmaxf(x[i], 0.0f) + EPSF, g);
        y[i] = __builtin_bit_cast(unsigned short, h);
    }
}

// Zernike-like polynomial basis, bit-exact mask vs numpy linspace semantics.
__global__ void k_basis(float* __restrict__ ws) {
    __shared__ float red[256];
    __shared__ float srms[NZ];
    __shared__ float scnt;
    float* basis = ws + BASIS_OFF;
    float* mask  = ws + MASK_OFF;
    int tid = threadIdx.x;
    double lsq[NZ];
    #pragma unroll
    for (int z = 0; z < NZ; ++z) lsq[z] = 0.0;
    double lcnt = 0.0;
    for (int pix = tid; pix < KK; pix += 256) {
        int i = pix / 31, j = pix - i * 31;
        double x = (j == 30) ? 1.0 : (-1.0 + (double)j * (2.0 / 30.0));
        double y = (i == 30) ? 1.0 : (-1.0 + (double)i * (2.0 / 30.0));
        double r2 = x * x + y * y;
        float m = (r2 <= 1.0) ? 1.0f : 0.0f;
        mask[pix] = m;
        lcnt += (double)m;
        #pragma unroll
        for (int deg = 1; deg <= 4; ++deg) {
            #pragma unroll
            for (int ii = 0; ii <= deg; ++ii) {
                const int z = deg * (deg + 1) / 2 - 1 + ii;
                double px = 1.0, py = 1.0;
                #pragma unroll
                for (int t = 0; t < deg - ii; ++t) px *= x;
                #pragma unroll
                for (int t = 0; t < ii; ++t) py *= y;
                float bf = (float)(px * py) * m;
                basis[z * KK + pix] = bf;
                lsq[z] += (double)bf * (double)bf;
            }
        }
    }
    for (int q = 0; q < NZ + 1; ++q) {
        red[tid] = (q < NZ) ? (float)lsq[q] : (float)lcnt;
        __syncthreads();
        for (int s = 128; s > 0; s >>= 1) {
            if (tid < s) red[tid] += red[tid + s];
            __syncthreads();
        }
        if (tid == 0) { if (q < NZ) srms[q] = red[0]; else scnt = red[0]; }
        __syncthreads();
    }
    if (tid < NZ) srms[tid] = sqrtf(srms[tid] / scnt) + 1e-8f;
    __syncthreads();
    for (int pix = tid; pix < KK; pix += 256) {
        #pragma unroll
        for (int z = 0; z < NZ; ++z)
            basis[z * KK + pix] = basis[z * KK + pix] / srms[z];
    }
}

// 121 unique coords (batch-tiled in reference), one block of 64 per coord.
__global__ void k_mlp(const float* __restrict__ w1, const float* __restrict__ b1,
                      const float* __restrict__ w2, const float* __restrict__ b2,
                      const float* __restrict__ w3, const float* __restrict__ b3,
                      float* __restrict__ ws) {
    __shared__ float h1[HID], h2v[HID];
    int n = blockIdx.x, t = threadIdx.x;
    int a = n / NHW, bw = n - a * NHW;
    float gy = (float)((((double)(a * 64)  + 64.0) / 768.0) * 2.0 - 1.0);
    float gx = (float)((((double)(bw * 64) + 64.0) / 768.0) * 2.0 - 1.0);
    h1[t] = tanhf(gy * w1[t] + gx * w1[HID + t] + b1[t]);
    __syncthreads();
    float acc2 = b2[t];
    for (int k = 0; k < HID; ++k) acc2 += h1[k] * w2[k * HID + t];
    h2v[t] = tanhf(acc2);
    __syncthreads();
    if (t < NZ) {
        float acc3 = b3[t];
        for (int k = 0; k < HID; ++k) acc3 += h2v[k] * w3[k * NZ + t];
        ws[COEF_OFF + n * NZ + t] = acc3;
    }
}

// One block per (n,c): phase -> field -> 31-pt row DFT -> col DFT -> |F|^2,
// normalize; fftshift+flip folded. Output: parity-packed padded kernel
// columns for k_conv's A-fragments. Kcolpad[x] = K[x-31, v] (0 outside);
// parity p, dword i holds f16 pair (Kcolpad[2i+p], Kcolpad[2i+p+1]).
__global__ void k_psf(float* __restrict__ ws) {
    __shared__ float fre[KK], fim[KK], gre[KK], gim[KK], sS[KK];
    __shared__ float twc[KS], tws[KS], cf[NZ], red[128];
    int blk = blockIdx.x;
    int n = blk / 3, c = blk - n * 3;
    int tid = threadIdx.x;
    const float* basis = ws + BASIS_OFF;
    const float* mask  = ws + MASK_OFF;
    if (tid < NZ) cf[tid] = ws[COEF_OFF + n * NZ + tid];
    if (tid < KS) {
        float ang = -6.283185307179586f * (float)tid / 31.0f;
        float s, co;
        sincosf(ang, &s, &co);
        twc[tid] = co; tws[tid] = s;
    }
    const float wl = (c == 0) ? (0.53f / 0.61f) : ((c == 1) ? 1.0f : (0.53f / 0.47f));
    __syncthreads();
    for (int pix = tid; pix < KK; pix += 128) {
        float ph = 0.0f;
        #pragma unroll
        for (int z = 0; z < NZ; ++z) ph += cf[z] * basis[z * KK + pix];
        float ang = 6.283185307179586f * (wl * ph);
        float s, co;
        sincosf(ang, &s, &co);
        float m = mask[pix];
        fre[pix] = m * co;
        fim[pix] = m * s;
    }
    __syncthreads();
    for (int pix = tid; pix < KK; pix += 128) {
        int i = pix / 31, q = pix - i * 31;
        float ar = 0.0f, ai = 0.0f;
        int m = 0;
        const float* br = &fre[i * 31];
        const float* bi = &fim[i * 31];
        #pragma unroll
        for (int j = 0; j < 31; ++j) {
            float tc = twc[m], ts = tws[m];
            float xr = br[j], xi = bi[j];
            ar += xr * tc - xi * ts;
            ai += xr * ts + xi * tc;
            m += q; if (m >= 31) m -= 31;
        }
        gre[pix] = ar; gim[pix] = ai;
    }
    __syncthreads();
    float lsum = 0.0f;
    for (int pix = tid; pix < KK; pix += 128) {
        int p = pix / 31, q = pix - p * 31;
        float ar = 0.0f, ai = 0.0f;
        int m = 0;
        #pragma unroll
        for (int i2 = 0; i2 < 31; ++i2) {
            float tc = twc[m], ts = tws[m];
            float xr = gre[i2 * 31 + q], xi = gim[i2 * 31 + q];
            ar += xr * tc - xi * ts;
            ai += xr * ts + xi * tc;
            m += p; if (m >= 31) m -= 31;
        }
        float sv = ar * ar + ai * ai;
        sS[pix] = sv;
        lsum += sv;
    }
    red[tid] = lsum;
    __syncthreads();
    for (int s = 64; s > 0; s >>= 1) {
        if (tid < s) red[tid] += red[tid + s];
        __syncthreads();
    }
    float tot = red[0] + EPSF;
    unsigned* kp = (unsigned*)(ws + KERN_OFF) + (n * 3 + c) * KNC_DW;
    for (int idx = tid; idx < 31 * 106; idx += 128) {
        int v = idx / 106, rem = idx - v * 106;
        int p = rem / 53, i = rem - p * 53;
        int iv = 15 - v; if (iv < 0) iv += 31;
        int t0 = 2 * i + p - 31, t1 = t0 + 1;
        float k0 = 0.0f, k1 = 0.0f;
        if ((unsigned)t0 < 31u) {
            int iu = 15 - t0; if (iu < 0) iu += 31;
            k0 = sS[iu * 31 + iv] / tot;
        }
        if ((unsigned)t1 < 31u) {
            int iu = 15 - t1; if (iu < 0) iu += 31;
            k1 = sS[iu * 31 + iv] / tot;
        }
        kp[idx] = pack_h2(k0, k1);
    }
}

// Hot kernel, R9: MFMA banded-Toeplitz with A-fragments from a precomputed
// parity-packed global table (L1-hot, 13 KB per (n,c)) -> no kcp LDS, no
// alignbit chain; LDS drops to 51.8 KB -> 3 blocks/CU (12 waves).
// Per wave-v: 4 global_load_dwordx4 (A) + 20 ds_read_b64 (B) + 16 MFMA.
// mfma_f32_32x32x16_f16: A[m=lane&31][k=(lane>>5)*8+e], B[k][n=lane&31],
// C/D: col=lane&31, row=(reg&3)+8*(reg>>2)+4*(lane>>5)  [verified m74/m101].
__global__ __launch_bounds__(256, 3) void k_conv(const float* __restrict__ ws,
                                                 float* __restrict__ out) {
    __shared__ unsigned short sT[158 * 164];   // 51,824 B
    int unit = blockIdx.x;
    int bn = unit / 3, c = unit - bn * 3;
    int b = bn / NN, n = bn - b * NN;
    int a = n / NHW, bw = n - a * NHW;
    int tid = threadIdx.x;
    const unsigned* kpb = (const unsigned*)(ws + KERN_OFF) + (n * 3 + c) * KNC_DW;
    // slab: col-major f16, sT[col*164 + q] = Ppad[q, col] (zero-padded)
    const unsigned short* xlc =
        (const unsigned short*)ws + (size_t)(b * 3 + c) * (HH * HH);
    for (int i = tid; i < 158 * 158; i += 256) {
        int q = i / 158, col = i - q * 158;
        int pi = q - 15, pj = col - 15;
        unsigned short hv = 0;
        if ((unsigned)pi < 128u && (unsigned)pj < 128u)
            hv = xlc[(a * 64 + pi) * HH + bw * 64 + pj];
        sT[col * 164 + q] = hv;
    }
    for (int i = tid; i < 158 * 6; i += 256) {
        int q = 158 + i / 158, col = i % 158;
        sT[col * 164 + q] = 0;
    }
    __syncthreads();
    int lane = tid & 63;
    int wave = tid >> 6;          // = nt
    int nI = lane & 31;           // n (B/C col) and m (A row) index
    int k8 = lane >> 5;           // K-half selector
    int colbase = wave * 32 + nI; // output column
    f32x16 acc[4];
    #pragma unroll
    for (int m = 0; m < 4; ++m) acc[m] = (f32x16)(0.0f);
    #pragma unroll 1
    for (int v = 0; v < 31; ++v) {
        const unsigned* kv = kpb + v * 106;
        h8 A[4];
        #pragma unroll
        for (int o = 0; o < 4; ++o) {
            int tA = 16 * o + 8 * k8 - nI + 31;   // in [0, 87]
            int p = tA & 1, d0 = tA >> 1;
            uint4 u = *(const uint4_u*)(kv + p * 53 + d0);
            A[o] = __builtin_bit_cast(h8, u);
        }
        const unsigned short* cb = &sT[(colbase + v) * 164 + k8 * 8];
        #pragma unroll
        for (int kb = 0; kb < 10; ++kb) {
            const uint2* pp = (const uint2*)(cb + kb * 16);   // 8B-aligned
            uint2 lo = pp[0], hi = pp[1];
            uint4 u; u.x = lo.x; u.y = lo.y; u.z = hi.x; u.w = hi.y;
            h8 B = __builtin_bit_cast(h8, u);
            #pragma unroll
            for (int mt = 0; mt < 4; ++mt) {
                int o = kb - 2 * mt;               // compile-time folded
                if (o >= 0 && o < 4)
                    acc[mt] = __builtin_amdgcn_mfma_f32_32x32x16_f16(
                        A[o], B, acc[mt], 0, 0, 0);
            }
        }
    }
    float wcol = hann_f(colbase);
    float* ob = out + (size_t)(b * 3 + c) * (HH * HH) + (size_t)(a * 64) * HH + bw * 64;
    #pragma unroll
    for (int mt = 0; mt < 4; ++mt) {
        #pragma unroll
        for (int reg = 0; reg < 16; ++reg) {
            int r = mt * 32 + (reg & 3) + 8 * (reg >> 2) + 4 * k8;
            atomicAdd(ob + r * HH + colbase, acc[mt][reg] * hann_f(r) * wcol);
        }
    }
}

// Overlap-add normalization (norm is separable: sh[y]*sw[x]) + inverse gamma.
__global__ void k_final(float* __restrict__ out, const float* __restrict__ gp, int ntot) {
    float ig = 1.0f / (*gp);
    for (int idx = blockIdx.x * blockDim.x + threadIdx.x; idx < ntot;
         idx += gridDim.x * blockDim.x) {
        int x = idx % HH;
        int y = (idx / HH) % HH;
        int ay = y >> 6, ry = y - (ay << 6);
        float sh = 0.0f;
        if (ay <= 10) sh += hann_f(ry);
        if (ay >= 1)  sh += hann_f(ry + 64);
        int ax = x >> 6, rx = x - (ax << 6);
        float sw = 0.0f;
        if (ax <= 10) sw += hann_f(rx);
        if (ax >= 1)  sw += hann_f(rx + 64);
        float v = out[idx] / (sh * sw + EPSF);
        out[idx] = __powf(fmaxf(v, 0.0f) + EPSF, ig);
    }
}

extern "C" void kernel_launch(void* const* d_in, const int* in_sizes, int n_in,
                              void* d_out, int out_size, void* d_ws, size_t ws_size,
                              hipStream_t stream) {
    const float* x  = (const float*)d_in[0];
    const float* w1 = (const float*)d_in[1];
    const float* b1 = (const float*)d_in[2];
    const float* w2 = (const float*)d_in[3];
    const float* b2 = (const float*)d_in[4];
    const float* w3 = (const float*)d_in[5];
    const float* b3 = (const float*)d_in[6];
    const float* gp = (const float*)d_in[7];
    float* out = (float*)d_out;
    float* ws  = (float*)d_ws;

    (void)hipMemsetAsync(d_out, 0, (size_t)out_size * sizeof(float), stream);
    int ntot = NB * NC * HH * HH;
    k_pow<<<4096, 256, 0, stream>>>(x, gp, (unsigned short*)(ws + XLIN_OFF), ntot);
    k_basis<<<1, 256, 0, stream>>>(ws);
    k_mlp<<<NN, 64, 0, stream>>>(w1, b1, w2, b2, w3, b3, ws);
    k_psf<<<NN * NC, 128, 0, stream>>>(ws);
    k_conv<<<NB * NN * NC, 256, 0, stream>>>(ws, out);
    k_final<<<4096, 256, 0, stream>>>(out, gp, ntot);
}

// Round 10
// 385.353 us; speedup vs baseline: 2.4282x; 1.0786x over previous
//
#include <hip/hip_runtime.h>
#include <math.h>

#define EPSF 1e-6f
#define NB   4
#define NC   3
#define HH   768
#define KS   31
#define KK   961
#define NHW  11
#define NN   121
#define NZ   14
#define HID  64

// workspace layout (float offsets). xlin stored as f16 (u16).
#define XLIN_OFF  0
#define XLIN_F    3538944                  // 7,077,888 u16 = 3,538,944 floats
#define BASIS_OFF (XLIN_OFF + XLIN_F)
#define MASK_OFF  (BASIS_OFF + 13456)      // basis 14*961=13454
#define COEF_OFF  (MASK_OFF + 964)         // mask 961
#define KERN_OFF  (COEF_OFF + 1696)        // parity-packed f16 tap tables
#define KNC_DW    (31 * 106)               // 3286 dwords per (n,c)
// total ws ~19 MB

typedef _Float16 h8 __attribute__((ext_vector_type(8)));
typedef float f32x16 __attribute__((ext_vector_type(16)));
typedef uint4 uint4_u __attribute__((aligned(4)));   // 4B-aligned 16B load

__device__ __forceinline__ unsigned pack_h2(float a, float b) {
    return __builtin_bit_cast(unsigned, __builtin_amdgcn_cvt_pkrtz(a, b));
}

__device__ __forceinline__ float hann_f(int p) {
    return 0.5f * (1.0f - cosf(6.283185307179586f * (float)p / 128.0f));
}

__global__ void k_pow(const float* __restrict__ x, const float* __restrict__ gp,
                      unsigned short* __restrict__ y, int n) {
    float g = *gp;
    for (int i = blockIdx.x * blockDim.x + threadIdx.x; i < n; i += gridDim.x * blockDim.x) {
        _Float16 h = (_Float16)__powf(fmaxf(x[i], 0.0f) + EPSF, g);
        y[i] = __builtin_bit_cast(unsigned short, h);
    }
}

// Zernike-like polynomial basis, bit-exact mask vs numpy linspace semantics.
__global__ void k_basis(float* __restrict__ ws) {
    __shared__ float red[256];
    __shared__ float srms[NZ];
    __shared__ float scnt;
    float* basis = ws + BASIS_OFF;
    float* mask  = ws + MASK_OFF;
    int tid = threadIdx.x;
    double lsq[NZ];
    #pragma unroll
    for (int z = 0; z < NZ; ++z) lsq[z] = 0.0;
    double lcnt = 0.0;
    for (int pix = tid; pix < KK; pix += 256) {
        int i = pix / 31, j = pix - i * 31;
        double x = (j == 30) ? 1.0 : (-1.0 + (double)j * (2.0 / 30.0));
        double y = (i == 30) ? 1.0 : (-1.0 + (double)i * (2.0 / 30.0));
        double r2 = x * x + y * y;
        float m = (r2 <= 1.0) ? 1.0f : 0.0f;
        mask[pix] = m;
        lcnt += (double)m;
        #pragma unroll
        for (int deg = 1; deg <= 4; ++deg) {
            #pragma unroll
            for (int ii = 0; ii <= deg; ++ii) {
                const int z = deg * (deg + 1) / 2 - 1 + ii;
                double px = 1.0, py = 1.0;
                #pragma unroll
                for (int t = 0; t < deg - ii; ++t) px *= x;
                #pragma unroll
                for (int t = 0; t < ii; ++t) py *= y;
                float bf = (float)(px * py) * m;
                basis[z * KK + pix] = bf;
                lsq[z] += (double)bf * (double)bf;
            }
        }
    }
    for (int q = 0; q < NZ + 1; ++q) {
        red[tid] = (q < NZ) ? (float)lsq[q] : (float)lcnt;
        __syncthreads();
        for (int s = 128; s > 0; s >>= 1) {
            if (tid < s) red[tid] += red[tid + s];
            __syncthreads();
        }
        if (tid == 0) { if (q < NZ) srms[q] = red[0]; else scnt = red[0]; }
        __syncthreads();
    }
    if (tid < NZ) srms[tid] = sqrtf(srms[tid] / scnt) + 1e-8f;
    __syncthreads();
    for (int pix = tid; pix < KK; pix += 256) {
        #pragma unroll
        for (int z = 0; z < NZ; ++z)
            basis[z * KK + pix] = basis[z * KK + pix] / srms[z];
    }
}

// 121 unique coords (batch-tiled in reference), one block of 64 per coord.
__global__ void k_mlp(const float* __restrict__ w1, const float* __restrict__ b1,
                      const float* __restrict__ w2, const float* __restrict__ b2,
                      const float* __restrict__ w3, const float* __restrict__ b3,
                      float* __restrict__ ws) {
    __shared__ float h1[HID], h2v[HID];
    int n = blockIdx.x, t = threadIdx.x;
    int a = n / NHW, bw = n - a * NHW;
    float gy = (float)((((double)(a * 64)  + 64.0) / 768.0) * 2.0 - 1.0);
    float gx = (float)((((double)(bw * 64) + 64.0) / 768.0) * 2.0 - 1.0);
    h1[t] = tanhf(gy * w1[t] + gx * w1[HID + t] + b1[t]);
    __syncthreads();
    float acc2 = b2[t];
    for (int k = 0; k < HID; ++k) acc2 += h1[k] * w2[k * HID + t];
    h2v[t] = tanhf(acc2);
    __syncthreads();
    if (t < NZ) {
        float acc3 = b3[t];
        for (int k = 0; k < HID; ++k) acc3 += h2v[k] * w3[k * NZ + t];
        ws[COEF_OFF + n * NZ + t] = acc3;
    }
}

// One block per (n,c): phase -> field -> 31-pt row DFT -> col DFT -> |F|^2,
// normalize; fftshift+flip folded. Output: parity-packed padded kernel
// columns (Kcolpad[x] = K[x-31, v], 0 outside; parity p dword i = f16 pair
// (Kcolpad[2i+p], Kcolpad[2i+p+1])) consumed as MFMA A-fragments in k_conv.
__global__ void k_psf(float* __restrict__ ws) {
    __shared__ float fre[KK], fim[KK], gre[KK], gim[KK], sS[KK];
    __shared__ float twc[KS], tws[KS], cf[NZ], red[128];
    int blk = blockIdx.x;
    int n = blk / 3, c = blk - n * 3;
    int tid = threadIdx.x;
    const float* basis = ws + BASIS_OFF;
    const float* mask  = ws + MASK_OFF;
    if (tid < NZ) cf[tid] = ws[COEF_OFF + n * NZ + tid];
    if (tid < KS) {
        float ang = -6.283185307179586f * (float)tid / 31.0f;
        float s, co;
        sincosf(ang, &s, &co);
        twc[tid] = co; tws[tid] = s;
    }
    const float wl = (c == 0) ? (0.53f / 0.61f) : ((c == 1) ? 1.0f : (0.53f / 0.47f));
    __syncthreads();
    for (int pix = tid; pix < KK; pix += 128) {
        float ph = 0.0f;
        #pragma unroll
        for (int z = 0; z < NZ; ++z) ph += cf[z] * basis[z * KK + pix];
        float ang = 6.283185307179586f * (wl * ph);
        float s, co;
        sincosf(ang, &s, &co);
        float m = mask[pix];
        fre[pix] = m * co;
        fim[pix] = m * s;
    }
    __syncthreads();
    for (int pix = tid; pix < KK; pix += 128) {
        int i = pix / 31, q = pix - i * 31;
        float ar = 0.0f, ai = 0.0f;
        int m = 0;
        const float* br = &fre[i * 31];
        const float* bi = &fim[i * 31];
        #pragma unroll
        for (int j = 0; j < 31; ++j) {
            float tc = twc[m], ts = tws[m];
            float xr = br[j], xi = bi[j];
            ar += xr * tc - xi * ts;
            ai += xr * ts + xi * tc;
            m += q; if (m >= 31) m -= 31;
        }
        gre[pix] = ar; gim[pix] = ai;
    }
    __syncthreads();
    float lsum = 0.0f;
    for (int pix = tid; pix < KK; pix += 128) {
        int p = pix / 31, q = pix - p * 31;
        float ar = 0.0f, ai = 0.0f;
        int m = 0;
        #pragma unroll
        for (int i2 = 0; i2 < 31; ++i2) {
            float tc = twc[m], ts = tws[m];
            float xr = gre[i2 * 31 + q], xi = gim[i2 * 31 + q];
            ar += xr * tc - xi * ts;
            ai += xr * ts + xi * tc;
            m += p; if (m >= 31) m -= 31;
        }
        float sv = ar * ar + ai * ai;
        sS[pix] = sv;
        lsum += sv;
    }
    red[tid] = lsum;
    __syncthreads();
    for (int s = 64; s > 0; s >>= 1) {
        if (tid < s) red[tid] += red[tid + s];
        __syncthreads();
    }
    float tot = red[0] + EPSF;
    unsigned* kp = (unsigned*)(ws + KERN_OFF) + (n * 3 + c) * KNC_DW;
    for (int idx = tid; idx < 31 * 106; idx += 128) {
        int v = idx / 106, rem = idx - v * 106;
        int p = rem / 53, i = rem - p * 53;
        int iv = 15 - v; if (iv < 0) iv += 31;
        int t0 = 2 * i + p - 31, t1 = t0 + 1;
        float k0 = 0.0f, k1 = 0.0f;
        if ((unsigned)t0 < 31u) {
            int iu = 15 - t0; if (iu < 0) iu += 31;
            k0 = sS[iu * 31 + iv] / tot;
        }
        if ((unsigned)t1 < 31u) {
            int iu = 15 - t1; if (iu < 0) iu += 31;
            k1 = sS[iu * 31 + iv] / tot;
        }
        kp[idx] = pack_h2(k0, k1);
    }
}

// Hot kernel, R10: output-stationary tiles — NO global atomics, k_final fused.
// One block per disjoint 64x64 output tile (b,c,ta,tx). The <=4 overlap-add
// contributors convolve the SAME input window (they differ only in PSF and
// Hann weight), so: stage one 94x94 slab, each wave owns a 32x32 quadrant
// and accumulates all 4 contributions (banded Toeplitz MFMA, A-table as R9),
// then weights, norms, gammas, and stores coalesced f32 — no atomics at all.
// Per wave-v: 4 ds_read_b64x2 (B, shared across p) + <=16 A-gathers + <=16
// MFMA; invalid edge contributions skipped by wave-uniform branch.
__global__ __launch_bounds__(256, 4) void k_conv(const float* __restrict__ ws,
                                                 const float* __restrict__ gp,
                                                 float* __restrict__ out) {
    __shared__ unsigned short sT[94 * 100];   // col-major sT[col*100+q], 18.8 KB
    int bid = blockIdx.x;
    int tile = bid % 144;
    int bc = bid / 144;            // b*3+c
    int c = bc % 3;
    int tx = tile % 12, ta = tile / 12;
    int y0 = ta * 64, x0 = tx * 64;
    int tid = threadIdx.x;
    const unsigned short* xlc = (const unsigned short*)ws + (size_t)bc * (HH * HH);
    // stage: sT[col][q] = xlin[y0+q-15, x0+col-15], zero outside; q in [94,96)=0
    for (int idx = tid; idx < 94 * 96; idx += 256) {
        int q = idx / 94, col = idx - (idx / 94) * 94;
        int pi = y0 + q - 15, pj = x0 + col - 15;
        unsigned short hv = 0;
        if (q < 94 && (unsigned)pi < 768u && (unsigned)pj < 768u)
            hv = xlc[pi * HH + pj];
        sT[col * 100 + q] = hv;
    }
    __syncthreads();
    int lane = tid & 63, wave = tid >> 6;
    int qy = wave >> 1, qx = wave & 1;    // quadrant
    int nI = lane & 31, k8 = lane >> 5;
    int cx = qx * 32 + nI;                // output col within tile
    bool vy0 = (ta <= 10), vy1 = (ta >= 1);
    bool vx0 = (tx <= 10), vx1 = (tx >= 1);
    bool valid[4] = { vy0 && vx0, vy0 && vx1, vy1 && vx0, vy1 && vx1 };
    const unsigned* kerbase = (const unsigned*)(ws + KERN_OFF);
    const unsigned* kp[4];
    #pragma unroll
    for (int p = 0; p < 4; ++p) {
        int aa = ta - (p >> 1), bb = tx - (p & 1);
        int n = valid[p] ? (aa * NHW + bb) : 0;
        kp[p] = kerbase + (n * 3 + c) * KNC_DW;
    }
    f32x16 acc[4];
    #pragma unroll
    for (int p = 0; p < 4; ++p) acc[p] = (f32x16)(0.0f);
    #pragma unroll 1
    for (int v = 0; v < 31; ++v) {
        // B fragments (patch; shared by all contributions): kb = 2*qy + o
        h8 B[4];
        const unsigned short* cb = &sT[(cx + v) * 100 + qy * 32 + k8 * 8];
        #pragma unroll
        for (int o = 0; o < 4; ++o) {
            const uint2* pp = (const uint2*)(cb + o * 16);   // 8B-aligned
            uint2 lo = pp[0], hi = pp[1];
            uint4 u; u.x = lo.x; u.y = lo.y; u.z = hi.x; u.w = hi.y;
            B[o] = __builtin_bit_cast(h8, u);
        }
        #pragma unroll
        for (int p = 0; p < 4; ++p) {
            if (valid[p]) {    // wave-uniform branch
                const unsigned* kv = kp[p] + v * 106;
                #pragma unroll
                for (int o = 0; o < 4; ++o) {
                    int tA = 16 * o + 8 * k8 - nI + 31;   // in [0, 87]
                    int par = tA & 1, d0 = tA >> 1;
                    uint4 u = *(const uint4_u*)(kv + par * 53 + d0);
                    h8 A = __builtin_bit_cast(h8, u);
                    acc[p] = __builtin_amdgcn_mfma_f32_32x32x16_f16(
                        A, B[o], acc[p], 0, 0, 0);
                }
            }
        }
    }
    // epilogue: window + separable norm + inverse gamma, coalesced stores
    float ig = 1.0f / (*gp);
    float wxc0 = vx0 ? hann_f(cx) : 0.0f;
    float wxc1 = vx1 ? hann_f(cx + 64) : 0.0f;
    float sw = wxc0 + wxc1;
    float* ob = out + (size_t)bc * (HH * HH) + (size_t)y0 * HH + x0;
    #pragma unroll
    for (int reg = 0; reg < 16; ++reg) {
        int rr = (reg & 3) + 8 * (reg >> 2) + 4 * k8;   // row in 32x32 tile
        int ry = qy * 32 + rr;
        float wy0 = vy0 ? hann_f(ry) : 0.0f;
        float wy1 = vy1 ? hann_f(ry + 64) : 0.0f;
        float val = wy0 * (wxc0 * acc[0][reg] + wxc1 * acc[1][reg])
                  + wy1 * (wxc0 * acc[2][reg] + wxc1 * acc[3][reg]);
        float vv = val / ((wy0 + wy1) * sw + EPSF);
        ob[(size_t)ry * HH + cx] = __powf(fmaxf(vv, 0.0f) + EPSF, ig);
    }
}

extern "C" void kernel_launch(void* const* d_in, const int* in_sizes, int n_in,
                              void* d_out, int out_size, void* d_ws, size_t ws_size,
                              hipStream_t stream) {
    const float* x  = (const float*)d_in[0];
    const float* w1 = (const float*)d_in[1];
    const float* b1 = (const float*)d_in[2];
    const float* w2 = (const float*)d_in[3];
    const float* b2 = (const float*)d_in[4];
    const float* w3 = (const float*)d_in[5];
    const float* b3 = (const float*)d_in[6];
    const float* gp = (const float*)d_in[7];
    float* out = (float*)d_out;
    float* ws  = (float*)d_ws;

    int ntot = NB * NC * HH * HH;
    k_pow<<<4096, 256, 0, stream>>>(x, gp, (unsigned short*)(ws + XLIN_OFF), ntot);
    k_basis<<<1, 256, 0, stream>>>(ws);
    k_mlp<<<NN, 64, 0, stream>>>(w1, b1, w2, b2, w3, b3, ws);
    k_psf<<<NN * NC, 128, 0, stream>>>(ws);
    k_conv<<<NB * NC * 144, 256, 0, stream>>>(ws, gp, out);
}